// Round 1
// baseline (5104.116 us; speedup 1.0000x reference)
//
#include <hip/hip_runtime.h>
#include <hip/hip_cooperative_groups.h>
#include <hip/hip_fp16.h>
#include <math.h>

namespace cg = cooperative_groups;

#define B_ 64
#define N_ 512
#define H_ 32
#define E_ 4
#define NSTEPS 5
#define KTOT 2048   // N_*E_

typedef _Float16 half8 __attribute__((ext_vector_type(8)));
typedef float   f32x4 __attribute__((ext_vector_type(4)));

struct Params {
    const float *x, *a, *m;
    const float *W_in, *b_in, *W_out, *b_out;
    const float *Wz, *bz, *Wr, *br, *Wt, *bt;
    const float *W1, *b1, *W2, *b2;
    float *out;
    float *h, *a_in, *a_out;
    _Float16 *sT_in_hi, *sT_in_lo, *sT_out_hi, *sT_out_lo;
};

// ================================================================= fused
// 1024 blocks x 256 threads, cooperative. Block mapping:
//   b = bid>>4 (batch), sub = bid&15, dir = sub&1, nblk = sub>>1 (n-chunk of 64)
// Phases per step: s-projection (dir==0 blocks) | einsum | gate, grid.sync between.
__global__ __launch_bounds__(256, 4) void k_fused(Params p) {
    cg::grid_group grid = cg::this_grid();
    const int bid = blockIdx.x;
    const int tid = threadIdx.x;

    // local __restrict__ views (codegen parity with the old standalone kernels)
    const float* __restrict__ mG   = p.m;
    float* __restrict__ hG         = p.h;
    float* __restrict__ aInG       = p.a_in;
    float* __restrict__ aOutG      = p.a_out;
    _Float16* __restrict__ siHi    = p.sT_in_hi;
    _Float16* __restrict__ siLo    = p.sT_in_lo;
    _Float16* __restrict__ soHi    = p.sT_out_hi;
    _Float16* __restrict__ soLo    = p.sT_out_lo;

    // ---- phase 0: h <- x  (1024*256 f32x4 covers all of h exactly)
    ((f32x4*)hG)[bid * 256 + tid] = ((const f32x4*)p.x)[bid * 256 + tid];
    grid.sync();

    const int b    = bid >> 4;
    const int sub  = bid & 15;
    const int dir  = sub & 1;
    const int nblk = sub >> 1;
    const int lane = tid & 63;
    const int w64  = __builtin_amdgcn_readfirstlane((int)(tid >> 6)); // 0..3

    __shared__ float cat[8][96];
    __shared__ float rh[8][32];
    __shared__ float hl[8][32];
    __shared__ float as[8];

    for (int s = 0; s < NSTEPS; s++) {
        // ---------------- s projection (8 blocks per batch: the dir==0 ones)
        if (dir == 0) {
            int n = nblk * 64 + lane;
            const float* __restrict__ hrow = hG + ((size_t)b * N_ + n) * H_;
            f32x4 hv[8];
#pragma unroll
            for (int c = 0; c < 8; c++) hv[c] = ((const f32x4*)hrow)[c];

#pragma unroll 4
            for (int o = 0; o < 32; o++) {
                int he = w64 * 32 + o;
                const f32x4* __restrict__ wr = (const f32x4*)(p.W_in + (size_t)he * H_);
                float acc = p.b_in[he];
#pragma unroll
                for (int c = 0; c < 8; c++) {
                    f32x4 wv = wr[c];
                    acc += hv[c][0]*wv[0] + hv[c][1]*wv[1] + hv[c][2]*wv[2] + hv[c][3]*wv[3];
                }
                int hh = he >> 2, e = he & 3;
                size_t idx = ((size_t)b * H_ + hh) * KTOT + e * N_ + n;
                _Float16 hi = (_Float16)acc;
                siHi[idx] = hi;
                siLo[idx] = (_Float16)(acc - (float)hi);
            }
#pragma unroll 4
            for (int o = 0; o < 32; o++) {
                int he = w64 * 32 + o;
                const f32x4* __restrict__ wr = (const f32x4*)(p.W_out + (size_t)he * H_);
                float acc = p.b_out[he];
#pragma unroll
                for (int c = 0; c < 8; c++) {
                    f32x4 wv = wr[c];
                    acc += hv[c][0]*wv[0] + hv[c][1]*wv[1] + hv[c][2]*wv[2] + hv[c][3]*wv[3];
                }
                int hh = he >> 2, e = he & 3;
                size_t idx = ((size_t)b * H_ + hh) * KTOT + e * N_ + n;
                _Float16 hi = (_Float16)acc;
                soHi[idx] = hi;
                soLo[idx] = (_Float16)(acc - (float)hi);
            }
        }
        grid.sync();

        // ---------------- einsum: a[b,n,h] = sum_k m[b,n,k] * sT[b][h][k]
        {
            int l15  = lane & 15;
            int quad = lane >> 4;
            int n0   = nblk * 64;

            const _Float16* __restrict__ sHi = (dir ? soHi : siHi) + (size_t)b * H_ * KTOT;
            const _Float16* __restrict__ sLo = (dir ? soLo : siLo) + (size_t)b * H_ * KTOT;
            float* __restrict__ aout = dir ? aOutG : aInG;

            int row = n0 + w64 * 16 + l15;
            const float* __restrict__ mrow =
                mG + ((size_t)b * N_ + row) * (2 * KTOT) + (size_t)dir * KTOT;

            f32x4 acc0 = {0.f,0.f,0.f,0.f}, acc1 = {0.f,0.f,0.f,0.f};

#pragma unroll 2
            for (int ks = 0; ks < KTOT; ks += 32) {
                int ko = ks + quad * 8;
                f32x4 a0 = *(const f32x4*)(mrow + ko);
                f32x4 a1 = *(const f32x4*)(mrow + ko + 4);
                half8 Bhi0 = *(const half8*)(sHi + (size_t)l15        * KTOT + ko);
                half8 Bhi1 = *(const half8*)(sHi + (size_t)(l15 + 16) * KTOT + ko);
                half8 Blo0 = *(const half8*)(sLo + (size_t)l15        * KTOT + ko);
                half8 Blo1 = *(const half8*)(sLo + (size_t)(l15 + 16) * KTOT + ko);

                half8 Ahi, Alo;
#pragma unroll
                for (int j = 0; j < 4; j++) {
                    float v0 = a0[j], v1 = a1[j];
                    _Float16 h0 = (_Float16)v0, h1 = (_Float16)v1;
                    Ahi[j]     = h0;
                    Ahi[j + 4] = h1;
                    Alo[j]     = (_Float16)(v0 - (float)h0);
                    Alo[j + 4] = (_Float16)(v1 - (float)h1);
                }
                acc0 = __builtin_amdgcn_mfma_f32_16x16x32_f16(Ahi, Bhi0, acc0, 0, 0, 0);
                acc1 = __builtin_amdgcn_mfma_f32_16x16x32_f16(Ahi, Bhi1, acc1, 0, 0, 0);
                acc0 = __builtin_amdgcn_mfma_f32_16x16x32_f16(Ahi, Blo0, acc0, 0, 0, 0);
                acc1 = __builtin_amdgcn_mfma_f32_16x16x32_f16(Ahi, Blo1, acc1, 0, 0, 0);
                acc0 = __builtin_amdgcn_mfma_f32_16x16x32_f16(Alo, Bhi0, acc0, 0, 0, 0);
                acc1 = __builtin_amdgcn_mfma_f32_16x16x32_f16(Alo, Bhi1, acc1, 0, 0, 0);
            }

#pragma unroll
            for (int r = 0; r < 4; r++) {
                size_t rr = (size_t)b * N_ + (n0 + w64 * 16 + quad * 4 + r);
                aout[rr * H_ + l15]      = acc0[r];
                aout[rr * H_ + 16 + l15] = acc1[r];
            }
        }
        grid.sync();

        // ---------------- GRU gates: 32 rows per block, 4 passes of 8
        for (int pp = 0; pp < 4; pp++) {
            int base = bid * 32 + pp * 8;
            for (int idx = tid; idx < 768; idx += 256) {
                int r = idx / 96, c = idx - r * 96;
                size_t rowi = (size_t)(base + r);
                float v;
                if (c < 32)      v = aInG [rowi * 32 + c];
                else if (c < 64) v = aOutG[rowi * 32 + (c - 32)];
                else             v = hG[rowi * 32 + (c - 64)];
                cat[r][c] = v;
            }
            __syncthreads();

            int r = tid >> 5, i = tid & 31;
            float az = p.bz[i], ar = p.br[i];
            const f32x4* __restrict__ wzr = (const f32x4*)(p.Wz + (size_t)i * 96);
            const f32x4* __restrict__ wrr = (const f32x4*)(p.Wr + (size_t)i * 96);
            const f32x4* crow = (const f32x4*)cat[r];
#pragma unroll
            for (int kc = 0; kc < 24; kc++) {
                f32x4 cv = crow[kc];
                f32x4 wz = wzr[kc];
                f32x4 wrv = wrr[kc];
                az += cv[0]*wz[0] + cv[1]*wz[1] + cv[2]*wz[2] + cv[3]*wz[3];
                ar += cv[0]*wrv[0] + cv[1]*wrv[1] + cv[2]*wrv[2] + cv[3]*wrv[3];
            }
            float z  = 1.f / (1.f + __expf(-az));
            float rg = 1.f / (1.f + __expf(-ar));
            float hold = cat[r][64 + i];
            rh[r][i] = rg * hold;
            __syncthreads();

            float at = p.bt[i];
            const f32x4* __restrict__ wtr = (const f32x4*)(p.Wt + (size_t)i * 96);
#pragma unroll
            for (int kc = 0; kc < 16; kc++) {
                f32x4 cv = crow[kc];
                f32x4 wt = wtr[kc];
                at += cv[0]*wt[0] + cv[1]*wt[1] + cv[2]*wt[2] + cv[3]*wt[3];
            }
            const f32x4* rrow = (const f32x4*)rh[r];
#pragma unroll
            for (int kc = 0; kc < 8; kc++) {
                f32x4 cv = rrow[kc];
                f32x4 wt = wtr[16 + kc];
                at += cv[0]*wt[0] + cv[1]*wt[1] + cv[2]*wt[2] + cv[3]*wt[3];
            }
            float hh2 = tanhf(at);
            hG[(size_t)(base + r) * 32 + i] = (1.f - z) * hold + z * hh2;
            __syncthreads();   // protect cat/rh reuse next pass
        }
        grid.sync();
    }

    // ---------------- readout: 32 rows per block, 4 passes of 8
    for (int pp = 0; pp < 4; pp++) {
        int base = bid * 32 + pp * 8;
        {
            int r = tid >> 5, c = tid & 31;
            hl[r][c] = hG[(size_t)(base + r) * 32 + c];
            if (tid < 8) as[tid] = p.a[base + tid];
        }
        __syncthreads();
        int r = tid >> 5, j = tid & 31;
        float acc = p.b1[j];
        const float* __restrict__ w1r = p.W1 + (size_t)j * 33;
#pragma unroll
        for (int i2 = 0; i2 < 32; i2++) acc += hl[r][i2] * w1r[i2];
        acc += as[r] * w1r[32];
        float o = tanhf(acc) * p.W2[j];
#pragma unroll
        for (int off = 16; off; off >>= 1) o += __shfl_xor(o, off, 32);
        if (j == 0) p.out[base + r] = o + p.b2[0];
        __syncthreads();   // protect hl/as reuse next pass
    }
}

// ================================================================= fallback
// (verbatim copies of the verified standalone kernels)
__global__ __launch_bounds__(256) void k_init_h(const float* __restrict__ x,
                                                float* __restrict__ h) {
    int i = blockIdx.x * blockDim.x + threadIdx.x;
    ((f32x4*)h)[i] = ((const f32x4*)x)[i];
}

__global__ __launch_bounds__(256) void k_s(const float* __restrict__ hstate,
                                           const float* __restrict__ W_in,
                                           const float* __restrict__ b_in,
                                           const float* __restrict__ W_out,
                                           const float* __restrict__ b_out,
                                           _Float16* __restrict__ sT_in_hi,
                                           _Float16* __restrict__ sT_in_lo,
                                           _Float16* __restrict__ sT_out_hi,
                                           _Float16* __restrict__ sT_out_lo) {
    int b  = blockIdx.x >> 3;
    int n0 = (blockIdx.x & 7) * 64;
    int lane = threadIdx.x & 63;
    int w = __builtin_amdgcn_readfirstlane((int)(threadIdx.x >> 6));
    int n = n0 + lane;

    const float* hrow = hstate + ((size_t)b * N_ + n) * H_;
    f32x4 hv[8];
#pragma unroll
    for (int c = 0; c < 8; c++) hv[c] = ((const f32x4*)hrow)[c];

#pragma unroll 4
    for (int o = 0; o < 32; o++) {
        int he = w * 32 + o;
        const f32x4* wr = (const f32x4*)(W_in + (size_t)he * H_);
        float acc = b_in[he];
#pragma unroll
        for (int c = 0; c < 8; c++) {
            f32x4 wv = wr[c];
            acc += hv[c][0]*wv[0] + hv[c][1]*wv[1] + hv[c][2]*wv[2] + hv[c][3]*wv[3];
        }
        int hh = he >> 2, e = he & 3;
        size_t idx = ((size_t)b * H_ + hh) * KTOT + e * N_ + n;
        _Float16 hi = (_Float16)acc;
        sT_in_hi[idx] = hi;
        sT_in_lo[idx] = (_Float16)(acc - (float)hi);
    }
#pragma unroll 4
    for (int o = 0; o < 32; o++) {
        int he = w * 32 + o;
        const f32x4* wr = (const f32x4*)(W_out + (size_t)he * H_);
        float acc = b_out[he];
#pragma unroll
        for (int c = 0; c < 8; c++) {
            f32x4 wv = wr[c];
            acc += hv[c][0]*wv[0] + hv[c][1]*wv[1] + hv[c][2]*wv[2] + hv[c][3]*wv[3];
        }
        int hh = he >> 2, e = he & 3;
        size_t idx = ((size_t)b * H_ + hh) * KTOT + e * N_ + n;
        _Float16 hi = (_Float16)acc;
        sT_out_hi[idx] = hi;
        sT_out_lo[idx] = (_Float16)(acc - (float)hi);
    }
}

__global__ __launch_bounds__(256) void k_einsum(const float* __restrict__ m,
                                                const _Float16* __restrict__ sT_in_hi,
                                                const _Float16* __restrict__ sT_in_lo,
                                                const _Float16* __restrict__ sT_out_hi,
                                                const _Float16* __restrict__ sT_out_lo,
                                                float* __restrict__ a_in,
                                                float* __restrict__ a_out) {
    int dir = blockIdx.z;
    int b   = blockIdx.y;
    int n0  = blockIdx.x * 64;
    int tid  = threadIdx.x;
    int w    = tid >> 6;
    int lane = tid & 63;
    int l15  = lane & 15;
    int quad = lane >> 4;

    const _Float16* sHi = (dir ? sT_out_hi : sT_in_hi) + (size_t)b * H_ * KTOT;
    const _Float16* sLo = (dir ? sT_out_lo : sT_in_lo) + (size_t)b * H_ * KTOT;
    float* aout = dir ? a_out : a_in;

    int row = n0 + w * 16 + l15;
    const float* mrow = m + ((size_t)b * N_ + row) * (2 * KTOT) + (size_t)dir * KTOT;

    f32x4 acc0 = {0.f,0.f,0.f,0.f}, acc1 = {0.f,0.f,0.f,0.f};

#pragma unroll 2
    for (int ks = 0; ks < KTOT; ks += 32) {
        int ko = ks + quad * 8;
        f32x4 a0 = *(const f32x4*)(mrow + ko);
        f32x4 a1 = *(const f32x4*)(mrow + ko + 4);
        half8 Bhi0 = *(const half8*)(sHi + (size_t)l15        * KTOT + ko);
        half8 Bhi1 = *(const half8*)(sHi + (size_t)(l15 + 16) * KTOT + ko);
        half8 Blo0 = *(const half8*)(sLo + (size_t)l15        * KTOT + ko);
        half8 Blo1 = *(const half8*)(sLo + (size_t)(l15 + 16) * KTOT + ko);

        half8 Ahi, Alo;
#pragma unroll
        for (int j = 0; j < 4; j++) {
            float v0 = a0[j], v1 = a1[j];
            _Float16 h0 = (_Float16)v0, h1 = (_Float16)v1;
            Ahi[j]     = h0;
            Ahi[j + 4] = h1;
            Alo[j]     = (_Float16)(v0 - (float)h0);
            Alo[j + 4] = (_Float16)(v1 - (float)h1);
        }
        acc0 = __builtin_amdgcn_mfma_f32_16x16x32_f16(Ahi, Bhi0, acc0, 0, 0, 0);
        acc1 = __builtin_amdgcn_mfma_f32_16x16x32_f16(Ahi, Bhi1, acc1, 0, 0, 0);
        acc0 = __builtin_amdgcn_mfma_f32_16x16x32_f16(Ahi, Blo0, acc0, 0, 0, 0);
        acc1 = __builtin_amdgcn_mfma_f32_16x16x32_f16(Ahi, Blo1, acc1, 0, 0, 0);
        acc0 = __builtin_amdgcn_mfma_f32_16x16x32_f16(Alo, Bhi0, acc0, 0, 0, 0);
        acc1 = __builtin_amdgcn_mfma_f32_16x16x32_f16(Alo, Bhi1, acc1, 0, 0, 0);
    }

#pragma unroll
    for (int r = 0; r < 4; r++) {
        size_t rr = (size_t)b * N_ + (n0 + w * 16 + quad * 4 + r);
        aout[rr * H_ + l15]      = acc0[r];
        aout[rr * H_ + 16 + l15] = acc1[r];
    }
}

__global__ __launch_bounds__(256) void k_gate(const float* __restrict__ a_in,
                                              const float* __restrict__ a_out,
                                              float* __restrict__ hstate,
                                              const float* __restrict__ Wz,
                                              const float* __restrict__ bz,
                                              const float* __restrict__ Wr,
                                              const float* __restrict__ br,
                                              const float* __restrict__ Wt,
                                              const float* __restrict__ bt) {
    __shared__ float cat[8][96];
    __shared__ float rh[8][32];
    int base = blockIdx.x * 8;
    int t = threadIdx.x;

    for (int idx = t; idx < 768; idx += 256) {
        int r = idx / 96, c = idx - r * 96;
        size_t row = (size_t)(base + r);
        float v;
        if (c < 32)      v = a_in [row * 32 + c];
        else if (c < 64) v = a_out[row * 32 + (c - 32)];
        else             v = hstate[row * 32 + (c - 64)];
        cat[r][c] = v;
    }
    __syncthreads();

    int r = t >> 5, i = t & 31;
    float az = bz[i], ar = br[i];
    const f32x4* wzr = (const f32x4*)(Wz + (size_t)i * 96);
    const f32x4* wrr = (const f32x4*)(Wr + (size_t)i * 96);
    const f32x4* crow = (const f32x4*)cat[r];
#pragma unroll
    for (int kc = 0; kc < 24; kc++) {
        f32x4 cv = crow[kc];
        f32x4 wz = wzr[kc];
        f32x4 wr = wrr[kc];
        az += cv[0]*wz[0] + cv[1]*wz[1] + cv[2]*wz[2] + cv[3]*wz[3];
        ar += cv[0]*wr[0] + cv[1]*wr[1] + cv[2]*wr[2] + cv[3]*wr[3];
    }
    float z  = 1.f / (1.f + __expf(-az));
    float rg = 1.f / (1.f + __expf(-ar));
    float hold = cat[r][64 + i];
    rh[r][i] = rg * hold;
    __syncthreads();

    float at = bt[i];
    const f32x4* wtr = (const f32x4*)(Wt + (size_t)i * 96);
#pragma unroll
    for (int kc = 0; kc < 16; kc++) {
        f32x4 cv = crow[kc];
        f32x4 wt = wtr[kc];
        at += cv[0]*wt[0] + cv[1]*wt[1] + cv[2]*wt[2] + cv[3]*wt[3];
    }
    const f32x4* rrow = (const f32x4*)rh[r];
#pragma unroll
    for (int kc = 0; kc < 8; kc++) {
        f32x4 cv = rrow[kc];
        f32x4 wt = wtr[16 + kc];
        at += cv[0]*wt[0] + cv[1]*wt[1] + cv[2]*wt[2] + cv[3]*wt[3];
    }
    float hh = tanhf(at);
    hstate[(size_t)(base + r) * 32 + i] = (1.f - z) * hold + z * hh;
}

__global__ __launch_bounds__(256) void k_final(const float* __restrict__ hstate,
                                               const float* __restrict__ a,
                                               const float* __restrict__ W1,
                                               const float* __restrict__ b1,
                                               const float* __restrict__ W2,
                                               const float* __restrict__ b2,
                                               float* __restrict__ out) {
    __shared__ float hl[8][32];
    __shared__ float as[8];
    int base = blockIdx.x * 8;
    int t = threadIdx.x;
    {
        int r = t >> 5, c = t & 31;
        hl[r][c] = hstate[(size_t)(base + r) * 32 + c];
        if (t < 8) as[t] = a[base + t];
    }
    __syncthreads();
    int r = t >> 5, j = t & 31;
    float acc = b1[j];
    const float* w1r = W1 + (size_t)j * 33;
#pragma unroll
    for (int i2 = 0; i2 < 32; i2++) acc += hl[r][i2] * w1r[i2];
    acc += as[r] * w1r[32];
    float o = tanhf(acc) * W2[j];
#pragma unroll
    for (int off = 16; off; off >>= 1) o += __shfl_xor(o, off, 32);
    if (j == 0) out[base + r] = o + b2[0];
}

// ================================================================= launcher
extern "C" void kernel_launch(void* const* d_in, const int* in_sizes, int n_in,
                              void* d_out, int out_size, void* d_ws, size_t ws_size,
                              hipStream_t stream) {
    const float* x     = (const float*)d_in[0];
    const float* a     = (const float*)d_in[1];
    const float* m     = (const float*)d_in[2];
    const float* W_in  = (const float*)d_in[3];
    const float* b_in  = (const float*)d_in[4];
    const float* W_out = (const float*)d_in[5];
    const float* b_out = (const float*)d_in[6];
    const float* Wz    = (const float*)d_in[7];
    const float* bz    = (const float*)d_in[8];
    const float* Wr    = (const float*)d_in[9];
    const float* br    = (const float*)d_in[10];
    const float* Wt    = (const float*)d_in[11];
    const float* bt    = (const float*)d_in[12];
    const float* W1    = (const float*)d_in[13];
    const float* b1    = (const float*)d_in[14];
    const float* W2    = (const float*)d_in[15];
    const float* b2    = (const float*)d_in[16];
    float* out = (float*)d_out;

    char* ws = (char*)d_ws;
    float*    h         = (float*)(ws);
    float*    a_in      = (float*)(ws + ((size_t)4  << 20));
    float*    a_out     = (float*)(ws + ((size_t)8  << 20));
    _Float16* sT_in_hi  = (_Float16*)(ws + ((size_t)12 << 20));
    _Float16* sT_in_lo  = (_Float16*)(ws + ((size_t)20 << 20));
    _Float16* sT_out_hi = (_Float16*)(ws + ((size_t)28 << 20));
    _Float16* sT_out_lo = (_Float16*)(ws + ((size_t)36 << 20));

    Params prm;
    prm.x = x; prm.a = a; prm.m = m;
    prm.W_in = W_in; prm.b_in = b_in; prm.W_out = W_out; prm.b_out = b_out;
    prm.Wz = Wz; prm.bz = bz; prm.Wr = Wr; prm.br = br; prm.Wt = Wt; prm.bt = bt;
    prm.W1 = W1; prm.b1 = b1; prm.W2 = W2; prm.b2 = b2;
    prm.out = out;
    prm.h = h; prm.a_in = a_in; prm.a_out = a_out;
    prm.sT_in_hi = sT_in_hi; prm.sT_in_lo = sT_in_lo;
    prm.sT_out_hi = sT_out_hi; prm.sT_out_lo = sT_out_lo;

    static int coop_ok = -1;
    if (coop_ok < 0) {
        int v = 0;
        hipDeviceGetAttribute(&v, hipDeviceAttributeCooperativeLaunch, 0);
        coop_ok = v;
    }

    hipError_t err = hipErrorUnknown;
    if (coop_ok) {
        void* args[] = { (void*)&prm };
        err = hipLaunchCooperativeKernel((const void*)k_fused,
                                         dim3(1024), dim3(256), args, 0, stream);
    }
    if (err != hipSuccess) {
        (void)hipGetLastError();   // clear error state; run proven multi-kernel path
        k_init_h<<<1024, 256, 0, stream>>>(x, h);
        for (int s = 0; s < NSTEPS; s++) {
            k_s<<<512, 256, 0, stream>>>(h, W_in, b_in, W_out, b_out,
                                         sT_in_hi, sT_in_lo, sT_out_hi, sT_out_lo);
            k_einsum<<<dim3(8, 64, 2), 256, 0, stream>>>(m, sT_in_hi, sT_in_lo,
                                                         sT_out_hi, sT_out_lo,
                                                         a_in, a_out);
            k_gate<<<4096, 256, 0, stream>>>(a_in, a_out, h, Wz, bz, Wr, br, Wt, bt);
        }
        k_final<<<4096, 256, 0, stream>>>(h, a, W1, b1, W2, b2, out);
    }
}

// Round 2
// 2576.080 us; speedup vs baseline: 1.9813x; 1.9813x over previous
//
#include <hip/hip_runtime.h>
#include <hip/hip_fp16.h>
#include <math.h>

#define B_ 64
#define N_ 512
#define H_ 32
#define E_ 4
#define NSTEPS 5
#define KTOT 2048   // N_*E_

typedef _Float16 half8 __attribute__((ext_vector_type(8)));
typedef float   f32x4 __attribute__((ext_vector_type(4)));

// ---------------------------------------------------------------- init h <- x
__global__ __launch_bounds__(256) void k_init_h(const float* __restrict__ x,
                                                float* __restrict__ h) {
    int i = blockIdx.x * blockDim.x + threadIdx.x;   // 262144 float4s
    ((f32x4*)h)[i] = ((const f32x4*)x)[i];
}

// ---------------------------------------------------------------- m pre-pack
// Pack m (fp32, constant across steps) into MFMA A-fragment order, split fp16
// hi/lo, ONCE. Tile g = (b*2+dir)*8 + nblk covers rows n0=nblk*64..+63, full K.
// Within tile: wave w owns rows w*16..+15. Fragment f at (iter it, lane):
//   pHi[g*131072 + w*32768 + it*512 + lane*8 + j]
//     = fp16( m[b, n0+w*16+(lane&15), dir*2048 + it*32 + (lane>>4)*8 + j] )
// so the einsum reads 16B/lane, 1KB/wave, perfectly sequential.
#define PACK_STRIDE 260   // 16B-aligned row stride in LDS floats (4-float pad)
__global__ __launch_bounds__(256) void k_pack(const float* __restrict__ m,
                                              _Float16* __restrict__ pHi,
                                              _Float16* __restrict__ pLo) {
    __shared__ float lds[16 * PACK_STRIDE];
    int bid = blockIdx.x;              // 0..4095
    int g = bid >> 2, w = bid & 3;
    int b = g >> 4, dir = (g >> 3) & 1, nblk = g & 7;
    int t = threadIdx.x;

    const float* mbase = m + ((size_t)(b * N_ + nblk * 64 + w * 16) * (2 * KTOT))
                           + (size_t)dir * KTOT;
    size_t obase = (size_t)g * 131072 + (size_t)w * 32768;

    int row16 = t >> 4, seg = t & 15;      // read mapping: 16 threads per row
    int it2 = t >> 6, lane = t & 63;       // write mapping
    int quad = lane >> 4, l15 = lane & 15;

    for (int c = 0; c < 8; c++) {          // K-chunks of 256 floats
        {   // coalesced global read: each row's 1KB chunk, 64B per thread
            const f32x4* src = (const f32x4*)(mbase + (size_t)row16 * (2 * KTOT)
                                              + c * 256 + seg * 16);
            f32x4* dst = (f32x4*)(lds + row16 * PACK_STRIDE + seg * 16);
            dst[0] = src[0]; dst[1] = src[1]; dst[2] = src[2]; dst[3] = src[3];
        }
        __syncthreads();
#pragma unroll
        for (int rep = 0; rep < 2; rep++) {
            int itl = it2 + rep * 4;       // 0..7 within chunk
            const float* lr = lds + l15 * PACK_STRIDE + itl * 32 + quad * 8;
            half8 hi, lo;
#pragma unroll
            for (int j = 0; j < 8; j++) {
                float v = lr[j];
                _Float16 hh = (_Float16)v;
                hi[j] = hh;
                lo[j] = (_Float16)(v - (float)hh);
            }
            size_t o = obase + (size_t)(c * 8 + itl) * 512 + (size_t)lane * 8;
            *(half8*)(pHi + o) = hi;       // 1KB contiguous per wave
            *(half8*)(pLo + o) = lo;
        }
        __syncthreads();
    }
}

// ---------------------------------------------------------------- s projection
__global__ __launch_bounds__(256) void k_s(const float* __restrict__ hstate,
                                           const float* __restrict__ W_in,
                                           const float* __restrict__ b_in,
                                           const float* __restrict__ W_out,
                                           const float* __restrict__ b_out,
                                           _Float16* __restrict__ sT_in_hi,
                                           _Float16* __restrict__ sT_in_lo,
                                           _Float16* __restrict__ sT_out_hi,
                                           _Float16* __restrict__ sT_out_lo) {
    int b  = blockIdx.x >> 3;
    int n0 = (blockIdx.x & 7) * 64;
    int lane = threadIdx.x & 63;
    int w = __builtin_amdgcn_readfirstlane((int)(threadIdx.x >> 6)); // 0..3
    int n = n0 + lane;

    const float* hrow = hstate + ((size_t)b * N_ + n) * H_;
    f32x4 hv[8];
#pragma unroll
    for (int c = 0; c < 8; c++) hv[c] = ((const f32x4*)hrow)[c];

#pragma unroll 4
    for (int o = 0; o < 32; o++) {
        int he = w * 32 + o;
        const f32x4* wr = (const f32x4*)(W_in + (size_t)he * H_);
        float acc = b_in[he];
#pragma unroll
        for (int c = 0; c < 8; c++) {
            f32x4 wv = wr[c];
            acc += hv[c][0]*wv[0] + hv[c][1]*wv[1] + hv[c][2]*wv[2] + hv[c][3]*wv[3];
        }
        int hh = he >> 2, e = he & 3;
        size_t idx = ((size_t)b * H_ + hh) * KTOT + e * N_ + n;
        _Float16 hi = (_Float16)acc;
        sT_in_hi[idx] = hi;
        sT_in_lo[idx] = (_Float16)(acc - (float)hi);
    }
#pragma unroll 4
    for (int o = 0; o < 32; o++) {
        int he = w * 32 + o;
        const f32x4* wr = (const f32x4*)(W_out + (size_t)he * H_);
        float acc = b_out[he];
#pragma unroll
        for (int c = 0; c < 8; c++) {
            f32x4 wv = wr[c];
            acc += hv[c][0]*wv[0] + hv[c][1]*wv[1] + hv[c][2]*wv[2] + hv[c][3]*wv[3];
        }
        int hh = he >> 2, e = he & 3;
        size_t idx = ((size_t)b * H_ + hh) * KTOT + e * N_ + n;
        _Float16 hi = (_Float16)acc;
        sT_out_hi[idx] = hi;
        sT_out_lo[idx] = (_Float16)(acc - (float)hi);
    }
}

// ---------------------------------------------------------------- einsum (packed A)
__global__ __launch_bounds__(256) void k_einsum_p(const _Float16* __restrict__ pHi,
                                                  const _Float16* __restrict__ pLo,
                                                  const _Float16* __restrict__ sT_in_hi,
                                                  const _Float16* __restrict__ sT_in_lo,
                                                  const _Float16* __restrict__ sT_out_hi,
                                                  const _Float16* __restrict__ sT_out_lo,
                                                  float* __restrict__ a_in,
                                                  float* __restrict__ a_out) {
    int dir  = blockIdx.z;
    int b    = blockIdx.y;
    int nblk = blockIdx.x;
    int tid  = threadIdx.x;
    int w    = tid >> 6;
    int lane = tid & 63;
    int l15  = lane & 15;
    int quad = lane >> 4;

    const _Float16* sHi = (dir ? sT_out_hi : sT_in_hi) + (size_t)b * H_ * KTOT;
    const _Float16* sLo = (dir ? sT_out_lo : sT_in_lo) + (size_t)b * H_ * KTOT;
    float* aout = dir ? a_out : a_in;

    size_t g = (size_t)((b * 2 + dir) * 8 + nblk);
    const _Float16* mh = pHi + g * 131072 + (size_t)w * 32768 + (size_t)lane * 8;
    const _Float16* ml = pLo + g * 131072 + (size_t)w * 32768 + (size_t)lane * 8;

    f32x4 acc0 = {0.f,0.f,0.f,0.f}, acc1 = {0.f,0.f,0.f,0.f};

#pragma unroll 2
    for (int it = 0; it < 64; it++) {
        int ko = it * 32 + quad * 8;
        half8 Ahi = *(const half8*)(mh + (size_t)it * 512);
        half8 Alo = *(const half8*)(ml + (size_t)it * 512);
        half8 Bhi0 = *(const half8*)(sHi + (size_t)l15        * KTOT + ko);
        half8 Bhi1 = *(const half8*)(sHi + (size_t)(l15 + 16) * KTOT + ko);
        half8 Blo0 = *(const half8*)(sLo + (size_t)l15        * KTOT + ko);
        half8 Blo1 = *(const half8*)(sLo + (size_t)(l15 + 16) * KTOT + ko);

        acc0 = __builtin_amdgcn_mfma_f32_16x16x32_f16(Ahi, Bhi0, acc0, 0, 0, 0);
        acc1 = __builtin_amdgcn_mfma_f32_16x16x32_f16(Ahi, Bhi1, acc1, 0, 0, 0);
        acc0 = __builtin_amdgcn_mfma_f32_16x16x32_f16(Ahi, Blo0, acc0, 0, 0, 0);
        acc1 = __builtin_amdgcn_mfma_f32_16x16x32_f16(Ahi, Blo1, acc1, 0, 0, 0);
        acc0 = __builtin_amdgcn_mfma_f32_16x16x32_f16(Alo, Bhi0, acc0, 0, 0, 0);
        acc1 = __builtin_amdgcn_mfma_f32_16x16x32_f16(Alo, Bhi1, acc1, 0, 0, 0);
    }

    int n0 = nblk * 64;
#pragma unroll
    for (int r = 0; r < 4; r++) {
        size_t rr = (size_t)b * N_ + (n0 + w * 16 + quad * 4 + r);
        aout[rr * H_ + l15]      = acc0[r];
        aout[rr * H_ + 16 + l15] = acc1[r];
    }
}

// ---------------------------------------------------------------- einsum (fallback, unpacked)
__global__ __launch_bounds__(256) void k_einsum(const float* __restrict__ m,
                                                const _Float16* __restrict__ sT_in_hi,
                                                const _Float16* __restrict__ sT_in_lo,
                                                const _Float16* __restrict__ sT_out_hi,
                                                const _Float16* __restrict__ sT_out_lo,
                                                float* __restrict__ a_in,
                                                float* __restrict__ a_out) {
    int dir = blockIdx.z;
    int b   = blockIdx.y;
    int n0  = blockIdx.x * 64;
    int tid  = threadIdx.x;
    int w    = tid >> 6;
    int lane = tid & 63;
    int l15  = lane & 15;
    int quad = lane >> 4;

    const _Float16* sHi = (dir ? sT_out_hi : sT_in_hi) + (size_t)b * H_ * KTOT;
    const _Float16* sLo = (dir ? sT_out_lo : sT_in_lo) + (size_t)b * H_ * KTOT;
    float* aout = dir ? a_out : a_in;

    int row = n0 + w * 16 + l15;
    const float* mrow = m + ((size_t)b * N_ + row) * (2 * KTOT) + (size_t)dir * KTOT;

    f32x4 acc0 = {0.f,0.f,0.f,0.f}, acc1 = {0.f,0.f,0.f,0.f};

#pragma unroll 2
    for (int ks = 0; ks < KTOT; ks += 32) {
        int ko = ks + quad * 8;
        f32x4 a0 = *(const f32x4*)(mrow + ko);
        f32x4 a1 = *(const f32x4*)(mrow + ko + 4);
        half8 Bhi0 = *(const half8*)(sHi + (size_t)l15        * KTOT + ko);
        half8 Bhi1 = *(const half8*)(sHi + (size_t)(l15 + 16) * KTOT + ko);
        half8 Blo0 = *(const half8*)(sLo + (size_t)l15        * KTOT + ko);
        half8 Blo1 = *(const half8*)(sLo + (size_t)(l15 + 16) * KTOT + ko);

        half8 Ahi, Alo;
#pragma unroll
        for (int j = 0; j < 4; j++) {
            float v0 = a0[j], v1 = a1[j];
            _Float16 h0 = (_Float16)v0, h1 = (_Float16)v1;
            Ahi[j]     = h0;
            Ahi[j + 4] = h1;
            Alo[j]     = (_Float16)(v0 - (float)h0);
            Alo[j + 4] = (_Float16)(v1 - (float)h1);
        }
        acc0 = __builtin_amdgcn_mfma_f32_16x16x32_f16(Ahi, Bhi0, acc0, 0, 0, 0);
        acc1 = __builtin_amdgcn_mfma_f32_16x16x32_f16(Ahi, Bhi1, acc1, 0, 0, 0);
        acc0 = __builtin_amdgcn_mfma_f32_16x16x32_f16(Ahi, Blo0, acc0, 0, 0, 0);
        acc1 = __builtin_amdgcn_mfma_f32_16x16x32_f16(Ahi, Blo1, acc1, 0, 0, 0);
        acc0 = __builtin_amdgcn_mfma_f32_16x16x32_f16(Alo, Bhi0, acc0, 0, 0, 0);
        acc1 = __builtin_amdgcn_mfma_f32_16x16x32_f16(Alo, Bhi1, acc1, 0, 0, 0);
    }

#pragma unroll
    for (int r = 0; r < 4; r++) {
        size_t rr = (size_t)b * N_ + (n0 + w * 16 + quad * 4 + r);
        aout[rr * H_ + l15]      = acc0[r];
        aout[rr * H_ + 16 + l15] = acc1[r];
    }
}

// ---------------------------------------------------------------- GRU gates
__global__ __launch_bounds__(256) void k_gate(const float* __restrict__ a_in,
                                              const float* __restrict__ a_out,
                                              float* __restrict__ hstate,
                                              const float* __restrict__ Wz,
                                              const float* __restrict__ bz,
                                              const float* __restrict__ Wr,
                                              const float* __restrict__ br,
                                              const float* __restrict__ Wt,
                                              const float* __restrict__ bt) {
    __shared__ float cat[8][96];
    __shared__ float rh[8][32];
    int base = blockIdx.x * 8;     // flattened row b*512+n
    int t = threadIdx.x;

    for (int idx = t; idx < 768; idx += 256) {
        int r = idx / 96, c = idx - r * 96;
        size_t row = (size_t)(base + r);
        float v;
        if (c < 32)      v = a_in [row * 32 + c];
        else if (c < 64) v = a_out[row * 32 + (c - 32)];
        else             v = hstate[row * 32 + (c - 64)];
        cat[r][c] = v;
    }
    __syncthreads();

    int r = t >> 5, i = t & 31;
    float az = bz[i], ar = br[i];
    const f32x4* wzr = (const f32x4*)(Wz + (size_t)i * 96);
    const f32x4* wrr = (const f32x4*)(Wr + (size_t)i * 96);
    const f32x4* crow = (const f32x4*)cat[r];
#pragma unroll
    for (int kc = 0; kc < 24; kc++) {
        f32x4 cv = crow[kc];
        f32x4 wz = wzr[kc];
        f32x4 wr = wrr[kc];
        az += cv[0]*wz[0] + cv[1]*wz[1] + cv[2]*wz[2] + cv[3]*wz[3];
        ar += cv[0]*wr[0] + cv[1]*wr[1] + cv[2]*wr[2] + cv[3]*wr[3];
    }
    float z  = 1.f / (1.f + __expf(-az));
    float rg = 1.f / (1.f + __expf(-ar));
    float hold = cat[r][64 + i];
    rh[r][i] = rg * hold;
    __syncthreads();

    float at = bt[i];
    const f32x4* wtr = (const f32x4*)(Wt + (size_t)i * 96);
#pragma unroll
    for (int kc = 0; kc < 16; kc++) {     // a_in | a_out part
        f32x4 cv = crow[kc];
        f32x4 wt = wtr[kc];
        at += cv[0]*wt[0] + cv[1]*wt[1] + cv[2]*wt[2] + cv[3]*wt[3];
    }
    const f32x4* rrow = (const f32x4*)rh[r];
#pragma unroll
    for (int kc = 0; kc < 8; kc++) {      // r*h part
        f32x4 cv = rrow[kc];
        f32x4 wt = wtr[16 + kc];
        at += cv[0]*wt[0] + cv[1]*wt[1] + cv[2]*wt[2] + cv[3]*wt[3];
    }
    float hh = tanhf(at);
    hstate[(size_t)(base + r) * 32 + i] = (1.f - z) * hold + z * hh;
}

// ---------------------------------------------------------------- readout
__global__ __launch_bounds__(256) void k_final(const float* __restrict__ hstate,
                                               const float* __restrict__ a,
                                               const float* __restrict__ W1,
                                               const float* __restrict__ b1,
                                               const float* __restrict__ W2,
                                               const float* __restrict__ b2,
                                               float* __restrict__ out) {
    __shared__ float hl[8][32];
    __shared__ float as[8];
    int base = blockIdx.x * 8;
    int t = threadIdx.x;
    {
        int r = t >> 5, c = t & 31;
        hl[r][c] = hstate[(size_t)(base + r) * 32 + c];
        if (t < 8) as[t] = a[base + t];
    }
    __syncthreads();
    int r = t >> 5, j = t & 31;
    float acc = b1[j];
    const float* w1r = W1 + (size_t)j * 33;
#pragma unroll
    for (int i2 = 0; i2 < 32; i2++) acc += hl[r][i2] * w1r[i2];
    acc += as[r] * w1r[32];
    float o = tanhf(acc) * W2[j];
#pragma unroll
    for (int off = 16; off; off >>= 1) o += __shfl_xor(o, off, 32);
    if (j == 0) out[base + r] = o + b2[0];
}

// ---------------------------------------------------------------- launcher
extern "C" void kernel_launch(void* const* d_in, const int* in_sizes, int n_in,
                              void* d_out, int out_size, void* d_ws, size_t ws_size,
                              hipStream_t stream) {
    const float* x     = (const float*)d_in[0];
    const float* a     = (const float*)d_in[1];
    const float* m     = (const float*)d_in[2];
    const float* W_in  = (const float*)d_in[3];
    const float* b_in  = (const float*)d_in[4];
    const float* W_out = (const float*)d_in[5];
    const float* b_out = (const float*)d_in[6];
    const float* Wz    = (const float*)d_in[7];
    const float* bz    = (const float*)d_in[8];
    const float* Wr    = (const float*)d_in[9];
    const float* br    = (const float*)d_in[10];
    const float* Wt    = (const float*)d_in[11];
    const float* bt    = (const float*)d_in[12];
    const float* W1    = (const float*)d_in[13];
    const float* b1    = (const float*)d_in[14];
    const float* W2    = (const float*)d_in[15];
    const float* b2    = (const float*)d_in[16];
    float* out = (float*)d_out;

    char* ws = (char*)d_ws;
    float*    h         = (float*)(ws);                           // 4 MB
    float*    a_in      = (float*)(ws + ((size_t)4  << 20));      // 4 MB
    float*    a_out     = (float*)(ws + ((size_t)8  << 20));      // 4 MB
    _Float16* sT_in_hi  = (_Float16*)(ws + ((size_t)12 << 20));   // 8 MB
    _Float16* sT_in_lo  = (_Float16*)(ws + ((size_t)20 << 20));   // 8 MB
    _Float16* sT_out_hi = (_Float16*)(ws + ((size_t)28 << 20));   // 8 MB
    _Float16* sT_out_lo = (_Float16*)(ws + ((size_t)36 << 20));   // 8 MB (44 MB)
    _Float16* mPackHi   = (_Float16*)(ws + ((size_t)48  << 20));  // 256 MB
    _Float16* mPackLo   = (_Float16*)(ws + ((size_t)304 << 20));  // 256 MB (560 MB)

    const int use_pack = (ws_size >= ((size_t)560 << 20));

    k_init_h<<<1024, 256, 0, stream>>>(x, h);
    if (use_pack)
        k_pack<<<4096, 256, 0, stream>>>(m, mPackHi, mPackLo);

    for (int s = 0; s < NSTEPS; s++) {
        k_s<<<512, 256, 0, stream>>>(h, W_in, b_in, W_out, b_out,
                                     sT_in_hi, sT_in_lo, sT_out_hi, sT_out_lo);
        if (use_pack)
            k_einsum_p<<<dim3(8, 64, 2), 256, 0, stream>>>(mPackHi, mPackLo,
                                                           sT_in_hi, sT_in_lo,
                                                           sT_out_hi, sT_out_lo,
                                                           a_in, a_out);
        else
            k_einsum<<<dim3(8, 64, 2), 256, 0, stream>>>(m, sT_in_hi, sT_in_lo,
                                                         sT_out_hi, sT_out_lo,
                                                         a_in, a_out);
        k_gate<<<4096, 256, 0, stream>>>(a_in, a_out, h, Wz, bz, Wr, br, Wt, bt);
    }
    k_final<<<4096, 256, 0, stream>>>(h, a, W1, b1, W2, b2, out);
}

// Round 3
// 2530.225 us; speedup vs baseline: 2.0173x; 1.0181x over previous
//
#include <hip/hip_runtime.h>
#include <hip/hip_fp16.h>
#include <math.h>

#define B_ 64
#define N_ 512
#define H_ 32
#define E_ 4
#define NSTEPS 5
#define KTOT 2048       // N_*E_
#define KSPLIT 4
#define KCHUNK 512      // KTOT / KSPLIT
#define ASLAB (B_*N_*H_)   // floats per partial-a slab (4 MB)

typedef _Float16 half8 __attribute__((ext_vector_type(8)));
typedef float   f32x4 __attribute__((ext_vector_type(4)));

// ---------------------------------------------------------------- init h <- x
__global__ __launch_bounds__(256) void k_init_h(const float* __restrict__ x,
                                                float* __restrict__ h) {
    int i = blockIdx.x * blockDim.x + threadIdx.x;   // 262144 float4s
    ((f32x4*)h)[i] = ((const f32x4*)x)[i];
}

// ---------------------------------------------------------------- s projection
__global__ __launch_bounds__(256) void k_s(const float* __restrict__ hstate,
                                           const float* __restrict__ W_in,
                                           const float* __restrict__ b_in,
                                           const float* __restrict__ W_out,
                                           const float* __restrict__ b_out,
                                           _Float16* __restrict__ sT_in_hi,
                                           _Float16* __restrict__ sT_in_lo,
                                           _Float16* __restrict__ sT_out_hi,
                                           _Float16* __restrict__ sT_out_lo) {
    int b  = blockIdx.x >> 3;
    int n0 = (blockIdx.x & 7) * 64;
    int lane = threadIdx.x & 63;
    int w = __builtin_amdgcn_readfirstlane((int)(threadIdx.x >> 6)); // 0..3
    int n = n0 + lane;

    const float* hrow = hstate + ((size_t)b * N_ + n) * H_;
    f32x4 hv[8];
#pragma unroll
    for (int c = 0; c < 8; c++) hv[c] = ((const f32x4*)hrow)[c];

#pragma unroll 4
    for (int o = 0; o < 32; o++) {
        int he = w * 32 + o;                 // wave-uniform -> s_load for W
        const f32x4* wr = (const f32x4*)(W_in + (size_t)he * H_);
        float acc = b_in[he];
#pragma unroll
        for (int c = 0; c < 8; c++) {
            f32x4 wv = wr[c];
            acc += hv[c][0]*wv[0] + hv[c][1]*wv[1] + hv[c][2]*wv[2] + hv[c][3]*wv[3];
        }
        int hh = he >> 2, e = he & 3;
        size_t idx = ((size_t)b * H_ + hh) * KTOT + e * N_ + n;
        _Float16 hi = (_Float16)acc;
        sT_in_hi[idx] = hi;
        sT_in_lo[idx] = (_Float16)(acc - (float)hi);
    }
#pragma unroll 4
    for (int o = 0; o < 32; o++) {
        int he = w * 32 + o;
        const f32x4* wr = (const f32x4*)(W_out + (size_t)he * H_);
        float acc = b_out[he];
#pragma unroll
        for (int c = 0; c < 8; c++) {
            f32x4 wv = wr[c];
            acc += hv[c][0]*wv[0] + hv[c][1]*wv[1] + hv[c][2]*wv[2] + hv[c][3]*wv[3];
        }
        int hh = he >> 2, e = he & 3;
        size_t idx = ((size_t)b * H_ + hh) * KTOT + e * N_ + n;
        _Float16 hi = (_Float16)acc;
        sT_out_hi[idx] = hi;
        sT_out_lo[idx] = (_Float16)(acc - (float)hi);
    }
}

// ---------------------------------------------------------------- big einsum (K-split)
// apart slab z = dir*KSPLIT+split holds partial a over k in [split*512,(split+1)*512)
// grid: (8 nblk, 64 b, 8 z).  4096 blocks -> 8 blocks/CU -> 8 waves/SIMD.
__global__ __launch_bounds__(256) void k_einsum_s(const float* __restrict__ m,
                                                  const _Float16* __restrict__ sT_in_hi,
                                                  const _Float16* __restrict__ sT_in_lo,
                                                  const _Float16* __restrict__ sT_out_hi,
                                                  const _Float16* __restrict__ sT_out_lo,
                                                  float* __restrict__ apart) {
    int z     = blockIdx.z;          // 0..7
    int dir   = z >> 2;
    int split = z & 3;
    int b     = blockIdx.y;
    int n0    = blockIdx.x * 64;
    int tid   = threadIdx.x;
    int w     = tid >> 6;
    int lane  = tid & 63;
    int l15   = lane & 15;
    int quad  = lane >> 4;

    const _Float16* sHi = (dir ? sT_out_hi : sT_in_hi) + (size_t)b * H_ * KTOT;
    const _Float16* sLo = (dir ? sT_out_lo : sT_in_lo) + (size_t)b * H_ * KTOT;
    float* aout = apart + (size_t)z * ASLAB;

    int row = n0 + w * 16 + l15;     // A-frag row (m row)
    const float* mrow = m + ((size_t)b * N_ + row) * (2 * KTOT)
                          + (size_t)dir * KTOT + split * KCHUNK;

    f32x4 acc0 = {0.f,0.f,0.f,0.f}, acc1 = {0.f,0.f,0.f,0.f};

#pragma unroll 2
    for (int ks = 0; ks < KCHUNK; ks += 32) {
        int ko  = ks + quad * 8;                 // within-chunk m offset
        int kos = split * KCHUNK + ko;           // absolute sT k offset
        f32x4 a0 = *(const f32x4*)(mrow + ko);
        f32x4 a1 = *(const f32x4*)(mrow + ko + 4);
        half8 Bhi0 = *(const half8*)(sHi + (size_t)l15        * KTOT + kos);
        half8 Bhi1 = *(const half8*)(sHi + (size_t)(l15 + 16) * KTOT + kos);
        half8 Blo0 = *(const half8*)(sLo + (size_t)l15        * KTOT + kos);
        half8 Blo1 = *(const half8*)(sLo + (size_t)(l15 + 16) * KTOT + kos);

        half8 Ahi, Alo;
#pragma unroll
        for (int j = 0; j < 4; j++) {
            float v0 = a0[j], v1 = a1[j];
            _Float16 h0 = (_Float16)v0, h1 = (_Float16)v1;
            Ahi[j]     = h0;
            Ahi[j + 4] = h1;
            Alo[j]     = (_Float16)(v0 - (float)h0);
            Alo[j + 4] = (_Float16)(v1 - (float)h1);
        }
        acc0 = __builtin_amdgcn_mfma_f32_16x16x32_f16(Ahi, Bhi0, acc0, 0, 0, 0);
        acc1 = __builtin_amdgcn_mfma_f32_16x16x32_f16(Ahi, Bhi1, acc1, 0, 0, 0);
        acc0 = __builtin_amdgcn_mfma_f32_16x16x32_f16(Ahi, Blo0, acc0, 0, 0, 0);
        acc1 = __builtin_amdgcn_mfma_f32_16x16x32_f16(Ahi, Blo1, acc1, 0, 0, 0);
        acc0 = __builtin_amdgcn_mfma_f32_16x16x32_f16(Alo, Bhi0, acc0, 0, 0, 0);
        acc1 = __builtin_amdgcn_mfma_f32_16x16x32_f16(Alo, Bhi1, acc1, 0, 0, 0);
    }

    // D layout: row = quad*4 + r (within 16-row tile), col = l15 (+16 for acc1)
#pragma unroll
    for (int r = 0; r < 4; r++) {
        size_t rr = (size_t)b * N_ + (n0 + w * 16 + quad * 4 + r);
        aout[rr * H_ + l15]      = acc0[r];
        aout[rr * H_ + 16 + l15] = acc1[r];
    }
}

// ---------------------------------------------------------------- GRU gates
// reads the 8 partial-a slabs, sums splits in ascending-k order
__global__ __launch_bounds__(256) void k_gate(const float* __restrict__ apart,
                                              float* __restrict__ hstate,
                                              const float* __restrict__ Wz,
                                              const float* __restrict__ bz,
                                              const float* __restrict__ Wr,
                                              const float* __restrict__ br,
                                              const float* __restrict__ Wt,
                                              const float* __restrict__ bt) {
    __shared__ float cat[8][96];
    __shared__ float rh[8][32];
    int base = blockIdx.x * 8;     // flattened row b*512+n
    int t = threadIdx.x;

    for (int idx = t; idx < 768; idx += 256) {
        int r = idx / 96, c = idx - r * 96;
        size_t row = (size_t)(base + r);
        float v;
        if (c < 32) {
            const float* p = apart + row * 32 + c;            // dir=0 slabs 0..3
            v = ((p[0] + p[ASLAB]) + p[2 * (size_t)ASLAB]) + p[3 * (size_t)ASLAB];
        } else if (c < 64) {
            const float* p = apart + 4 * (size_t)ASLAB + row * 32 + (c - 32);
            v = ((p[0] + p[ASLAB]) + p[2 * (size_t)ASLAB]) + p[3 * (size_t)ASLAB];
        } else {
            v = hstate[row * 32 + (c - 64)];
        }
        cat[r][c] = v;
    }
    __syncthreads();

    int r = t >> 5, i = t & 31;
    float az = bz[i], ar = br[i];
    const f32x4* wzr = (const f32x4*)(Wz + (size_t)i * 96);
    const f32x4* wrr = (const f32x4*)(Wr + (size_t)i * 96);
    const f32x4* crow = (const f32x4*)cat[r];
#pragma unroll
    for (int kc = 0; kc < 24; kc++) {
        f32x4 cv = crow[kc];
        f32x4 wz = wzr[kc];
        f32x4 wr = wrr[kc];
        az += cv[0]*wz[0] + cv[1]*wz[1] + cv[2]*wz[2] + cv[3]*wz[3];
        ar += cv[0]*wr[0] + cv[1]*wr[1] + cv[2]*wr[2] + cv[3]*wr[3];
    }
    float z  = 1.f / (1.f + __expf(-az));
    float rg = 1.f / (1.f + __expf(-ar));
    float hold = cat[r][64 + i];
    rh[r][i] = rg * hold;
    __syncthreads();

    float at = bt[i];
    const f32x4* wtr = (const f32x4*)(Wt + (size_t)i * 96);
#pragma unroll
    for (int kc = 0; kc < 16; kc++) {     // a_in | a_out part
        f32x4 cv = crow[kc];
        f32x4 wt = wtr[kc];
        at += cv[0]*wt[0] + cv[1]*wt[1] + cv[2]*wt[2] + cv[3]*wt[3];
    }
    const f32x4* rrow = (const f32x4*)rh[r];
#pragma unroll
    for (int kc = 0; kc < 8; kc++) {      // r*h part
        f32x4 cv = rrow[kc];
        f32x4 wt = wtr[16 + kc];
        at += cv[0]*wt[0] + cv[1]*wt[1] + cv[2]*wt[2] + cv[3]*wt[3];
    }
    float hh = tanhf(at);
    hstate[(size_t)(base + r) * 32 + i] = (1.f - z) * hold + z * hh;
}

// ---------------------------------------------------------------- readout
__global__ __launch_bounds__(256) void k_final(const float* __restrict__ hstate,
                                               const float* __restrict__ a,
                                               const float* __restrict__ W1,
                                               const float* __restrict__ b1,
                                               const float* __restrict__ W2,
                                               const float* __restrict__ b2,
                                               float* __restrict__ out) {
    __shared__ float hl[8][32];
    __shared__ float as[8];
    int base = blockIdx.x * 8;
    int t = threadIdx.x;
    {
        int r = t >> 5, c = t & 31;
        hl[r][c] = hstate[(size_t)(base + r) * 32 + c];
        if (t < 8) as[t] = a[base + t];
    }
    __syncthreads();
    int r = t >> 5, j = t & 31;
    float acc = b1[j];
    const float* w1r = W1 + (size_t)j * 33;
#pragma unroll
    for (int i2 = 0; i2 < 32; i2++) acc += hl[r][i2] * w1r[i2];
    acc += as[r] * w1r[32];
    float o = tanhf(acc) * W2[j];
#pragma unroll
    for (int off = 16; off; off >>= 1) o += __shfl_xor(o, off, 32);
    if (j == 0) out[base + r] = o + b2[0];
}

// ---------------------------------------------------------------- launcher
extern "C" void kernel_launch(void* const* d_in, const int* in_sizes, int n_in,
                              void* d_out, int out_size, void* d_ws, size_t ws_size,
                              hipStream_t stream) {
    const float* x     = (const float*)d_in[0];
    const float* a     = (const float*)d_in[1];
    const float* m     = (const float*)d_in[2];
    const float* W_in  = (const float*)d_in[3];
    const float* b_in  = (const float*)d_in[4];
    const float* W_out = (const float*)d_in[5];
    const float* b_out = (const float*)d_in[6];
    const float* Wz    = (const float*)d_in[7];
    const float* bz    = (const float*)d_in[8];
    const float* Wr    = (const float*)d_in[9];
    const float* br    = (const float*)d_in[10];
    const float* Wt    = (const float*)d_in[11];
    const float* bt    = (const float*)d_in[12];
    const float* W1    = (const float*)d_in[13];
    const float* b1    = (const float*)d_in[14];
    const float* W2    = (const float*)d_in[15];
    const float* b2    = (const float*)d_in[16];
    float* out = (float*)d_out;

    char* ws = (char*)d_ws;
    float*    h         = (float*)(ws);                           // 4 MB
    float*    apart     = (float*)(ws + ((size_t)4  << 20));      // 32 MB (8 slabs)
    _Float16* sT_in_hi  = (_Float16*)(ws + ((size_t)36 << 20));   // 8 MB
    _Float16* sT_in_lo  = (_Float16*)(ws + ((size_t)44 << 20));   // 8 MB
    _Float16* sT_out_hi = (_Float16*)(ws + ((size_t)52 << 20));   // 8 MB
    _Float16* sT_out_lo = (_Float16*)(ws + ((size_t)60 << 20));   // 8 MB (68 MB)

    k_init_h<<<1024, 256, 0, stream>>>(x, h);
    for (int s = 0; s < NSTEPS; s++) {
        k_s<<<512, 256, 0, stream>>>(h, W_in, b_in, W_out, b_out,
                                     sT_in_hi, sT_in_lo, sT_out_hi, sT_out_lo);
        k_einsum_s<<<dim3(8, 64, 8), 256, 0, stream>>>(m, sT_in_hi, sT_in_lo,
                                                       sT_out_hi, sT_out_lo, apart);
        k_gate<<<4096, 256, 0, stream>>>(apart, h, Wz, bz, Wr, br, Wt, bt);
    }
    k_final<<<4096, 256, 0, stream>>>(h, a, W1, b1, W2, b2, out);
}

// Round 4
// 2401.424 us; speedup vs baseline: 2.1255x; 1.0536x over previous
//
#include <hip/hip_runtime.h>
#include <hip/hip_fp16.h>
#include <math.h>

#define B_ 64
#define N_ 512
#define H_ 32
#define E_ 4
#define NSTEPS 5
#define KTOT 2048       // N_*E_
#define KSPLIT 8
#define KCHUNK 256      // KTOT / KSPLIT
#define ASLAB (B_*N_*H_)   // floats per partial-a slab (4 MB)

typedef _Float16 half8 __attribute__((ext_vector_type(8)));
typedef float   f32x4 __attribute__((ext_vector_type(4)));

// ---------------------------------------------------------------- init h <- x
__global__ __launch_bounds__(256) void k_init_h(const float* __restrict__ x,
                                                float* __restrict__ h) {
    int i = blockIdx.x * blockDim.x + threadIdx.x;   // 262144 float4s
    ((f32x4*)h)[i] = ((const f32x4*)x)[i];
}

// ---------------------------------------------------------------- s projection
__global__ __launch_bounds__(256) void k_s(const float* __restrict__ hstate,
                                           const float* __restrict__ W_in,
                                           const float* __restrict__ b_in,
                                           const float* __restrict__ W_out,
                                           const float* __restrict__ b_out,
                                           _Float16* __restrict__ sT_in_hi,
                                           _Float16* __restrict__ sT_in_lo,
                                           _Float16* __restrict__ sT_out_hi,
                                           _Float16* __restrict__ sT_out_lo) {
    int b  = blockIdx.x >> 3;
    int n0 = (blockIdx.x & 7) * 64;
    int lane = threadIdx.x & 63;
    int w = __builtin_amdgcn_readfirstlane((int)(threadIdx.x >> 6)); // 0..3
    int n = n0 + lane;

    const float* hrow = hstate + ((size_t)b * N_ + n) * H_;
    f32x4 hv[8];
#pragma unroll
    for (int c = 0; c < 8; c++) hv[c] = ((const f32x4*)hrow)[c];

#pragma unroll 4
    for (int o = 0; o < 32; o++) {
        int he = w * 32 + o;                 // wave-uniform -> s_load for W
        const f32x4* wr = (const f32x4*)(W_in + (size_t)he * H_);
        float acc = b_in[he];
#pragma unroll
        for (int c = 0; c < 8; c++) {
            f32x4 wv = wr[c];
            acc += hv[c][0]*wv[0] + hv[c][1]*wv[1] + hv[c][2]*wv[2] + hv[c][3]*wv[3];
        }
        int hh = he >> 2, e = he & 3;
        size_t idx = ((size_t)b * H_ + hh) * KTOT + e * N_ + n;
        _Float16 hi = (_Float16)acc;
        sT_in_hi[idx] = hi;
        sT_in_lo[idx] = (_Float16)(acc - (float)hi);
    }
#pragma unroll 4
    for (int o = 0; o < 32; o++) {
        int he = w * 32 + o;
        const f32x4* wr = (const f32x4*)(W_out + (size_t)he * H_);
        float acc = b_out[he];
#pragma unroll
        for (int c = 0; c < 8; c++) {
            f32x4 wv = wr[c];
            acc += hv[c][0]*wv[0] + hv[c][1]*wv[1] + hv[c][2]*wv[2] + hv[c][3]*wv[3];
        }
        int hh = he >> 2, e = he & 3;
        size_t idx = ((size_t)b * H_ + hh) * KTOT + e * N_ + n;
        _Float16 hi = (_Float16)acc;
        sT_out_hi[idx] = hi;
        sT_out_lo[idx] = (_Float16)(acc - (float)hi);
    }
}

// ---------------------------------------------------------------- big einsum
// block = (split, b, dir). Stage sT slice (32 h-rows x 256 k, hi+lo = 32 KB)
// into XOR-swizzled LDS once, then loop 8 n-tiles of 64 rows.
// B-side global traffic: 1 GB/step -> 32 MB/step.
// apart slab z = dir*KSPLIT+split holds partial a over k in [split*256,+256).
__global__ __launch_bounds__(256) void k_einsum_l(const float* __restrict__ m,
                                                  const _Float16* __restrict__ sT_in_hi,
                                                  const _Float16* __restrict__ sT_in_lo,
                                                  const _Float16* __restrict__ sT_out_hi,
                                                  const _Float16* __restrict__ sT_out_lo,
                                                  float* __restrict__ apart) {
    int split = blockIdx.x;          // 0..7
    int b     = blockIdx.y;
    int dir   = blockIdx.z;
    int tid   = threadIdx.x;
    int w     = tid >> 6;
    int lane  = tid & 63;
    int l15   = lane & 15;
    int quad  = lane >> 4;

    __shared__ __align__(16) char smem[32768];   // [plane 2][row 32][512 B swz]

    const _Float16* sHi = (dir ? sT_out_hi : sT_in_hi)
                          + (size_t)b * H_ * KTOT + split * KCHUNK;
    const _Float16* sLo = (dir ? sT_out_lo : sT_in_lo)
                          + (size_t)b * H_ * KTOT + split * KCHUNK;

    // stage: 2048 chunks of 16B (hi plane then lo plane), swizzled write
    for (int i = tid; i < 2048; i += 256) {
        int plane = i >> 10, row = (i >> 5) & 31, c16 = i & 31;
        const _Float16* src = (plane ? sLo : sHi) + (size_t)row * KTOT + c16 * 8;
        half8 v = *(const half8*)src;
        int byte = plane * 16384 + row * 512 + ((c16 * 16) ^ ((row & 7) << 4));
        *(half8*)(smem + byte) = v;
    }
    __syncthreads();

    float* aout = apart + (size_t)(dir * KSPLIT + split) * ASLAB;
    int swz0 = (l15 & 7) << 4;       // same for row l15 and l15+16

#pragma unroll 2
    for (int pass = 0; pass < 8; pass++) {
        int n0 = pass * 64;
        const float* mrow = m + ((size_t)b * N_ + n0 + w * 16 + l15) * (2 * KTOT)
                              + (size_t)dir * KTOT + split * KCHUNK;

        f32x4 acc0 = {0.f,0.f,0.f,0.f}, acc1 = {0.f,0.f,0.f,0.f};

#pragma unroll 2
        for (int it = 0; it < 8; it++) {
            int ko = it * 32 + quad * 8;
            f32x4 a0 = *(const f32x4*)(mrow + ko);
            f32x4 a1 = *(const f32x4*)(mrow + ko + 4);

            int kb = it * 64 + quad * 16;          // byte offset in row
            int o0 = l15 * 512        + (kb ^ swz0);
            int o1 = (l15 + 16) * 512 + (kb ^ swz0);
            half8 Bhi0 = *(const half8*)(smem + o0);
            half8 Bhi1 = *(const half8*)(smem + o1);
            half8 Blo0 = *(const half8*)(smem + 16384 + o0);
            half8 Blo1 = *(const half8*)(smem + 16384 + o1);

            half8 Ahi, Alo;
#pragma unroll
            for (int j = 0; j < 4; j++) {
                float v0 = a0[j], v1 = a1[j];
                _Float16 h0 = (_Float16)v0, h1 = (_Float16)v1;
                Ahi[j]     = h0;
                Ahi[j + 4] = h1;
                Alo[j]     = (_Float16)(v0 - (float)h0);
                Alo[j + 4] = (_Float16)(v1 - (float)h1);
            }
            acc0 = __builtin_amdgcn_mfma_f32_16x16x32_f16(Ahi, Bhi0, acc0, 0, 0, 0);
            acc1 = __builtin_amdgcn_mfma_f32_16x16x32_f16(Ahi, Bhi1, acc1, 0, 0, 0);
            acc0 = __builtin_amdgcn_mfma_f32_16x16x32_f16(Ahi, Blo0, acc0, 0, 0, 0);
            acc1 = __builtin_amdgcn_mfma_f32_16x16x32_f16(Ahi, Blo1, acc1, 0, 0, 0);
            acc0 = __builtin_amdgcn_mfma_f32_16x16x32_f16(Alo, Bhi0, acc0, 0, 0, 0);
            acc1 = __builtin_amdgcn_mfma_f32_16x16x32_f16(Alo, Bhi1, acc1, 0, 0, 0);
        }

        // D layout: row = quad*4 + r (within 16-row tile), col = l15 (+16 for acc1)
#pragma unroll
        for (int r = 0; r < 4; r++) {
            size_t rr = (size_t)b * N_ + (n0 + w * 16 + quad * 4 + r);
            aout[rr * H_ + l15]      = acc0[r];
            aout[rr * H_ + 16 + l15] = acc1[r];
        }
    }
}

// ---------------------------------------------------------------- GRU gates
// reads the 16 partial-a slabs, sums splits in ascending-k order per dir
__global__ __launch_bounds__(256) void k_gate(const float* __restrict__ apart,
                                              float* __restrict__ hstate,
                                              const float* __restrict__ Wz,
                                              const float* __restrict__ bz,
                                              const float* __restrict__ Wr,
                                              const float* __restrict__ br,
                                              const float* __restrict__ Wt,
                                              const float* __restrict__ bt) {
    __shared__ float cat[8][96];
    __shared__ float rh[8][32];
    int base = blockIdx.x * 8;     // flattened row b*512+n
    int t = threadIdx.x;

    for (int idx = t; idx < 768; idx += 256) {
        int r = idx / 96, c = idx - r * 96;
        size_t row = (size_t)(base + r);
        float v;
        if (c < 64) {
            int d = c >> 5;                      // dir
            const float* p = apart + (size_t)d * KSPLIT * ASLAB + row * 32 + (c & 31);
            v = p[0];
#pragma unroll
            for (int s2 = 1; s2 < KSPLIT; s2++) v += p[(size_t)s2 * ASLAB];
        } else {
            v = hstate[row * 32 + (c - 64)];
        }
        cat[r][c] = v;
    }
    __syncthreads();

    int r = t >> 5, i = t & 31;
    float az = bz[i], ar = br[i];
    const f32x4* wzr = (const f32x4*)(Wz + (size_t)i * 96);
    const f32x4* wrr = (const f32x4*)(Wr + (size_t)i * 96);
    const f32x4* crow = (const f32x4*)cat[r];
#pragma unroll
    for (int kc = 0; kc < 24; kc++) {
        f32x4 cv = crow[kc];
        f32x4 wz = wzr[kc];
        f32x4 wr = wrr[kc];
        az += cv[0]*wz[0] + cv[1]*wz[1] + cv[2]*wz[2] + cv[3]*wz[3];
        ar += cv[0]*wr[0] + cv[1]*wr[1] + cv[2]*wr[2] + cv[3]*wr[3];
    }
    float z  = 1.f / (1.f + __expf(-az));
    float rg = 1.f / (1.f + __expf(-ar));
    float hold = cat[r][64 + i];
    rh[r][i] = rg * hold;
    __syncthreads();

    float at = bt[i];
    const f32x4* wtr = (const f32x4*)(Wt + (size_t)i * 96);
#pragma unroll
    for (int kc = 0; kc < 16; kc++) {     // a_in | a_out part
        f32x4 cv = crow[kc];
        f32x4 wt = wtr[kc];
        at += cv[0]*wt[0] + cv[1]*wt[1] + cv[2]*wt[2] + cv[3]*wt[3];
    }
    const f32x4* rrow = (const f32x4*)rh[r];
#pragma unroll
    for (int kc = 0; kc < 8; kc++) {      // r*h part
        f32x4 cv = rrow[kc];
        f32x4 wt = wtr[16 + kc];
        at += cv[0]*wt[0] + cv[1]*wt[1] + cv[2]*wt[2] + cv[3]*wt[3];
    }
    float hh = tanhf(at);
    hstate[(size_t)(base + r) * 32 + i] = (1.f - z) * hold + z * hh;
}

// ---------------------------------------------------------------- readout
__global__ __launch_bounds__(256) void k_final(const float* __restrict__ hstate,
                                               const float* __restrict__ a,
                                               const float* __restrict__ W1,
                                               const float* __restrict__ b1,
                                               const float* __restrict__ W2,
                                               const float* __restrict__ b2,
                                               float* __restrict__ out) {
    __shared__ float hl[8][32];
    __shared__ float as[8];
    int base = blockIdx.x * 8;
    int t = threadIdx.x;
    {
        int r = t >> 5, c = t & 31;
        hl[r][c] = hstate[(size_t)(base + r) * 32 + c];
        if (t < 8) as[t] = a[base + t];
    }
    __syncthreads();
    int r = t >> 5, j = t & 31;
    float acc = b1[j];
    const float* w1r = W1 + (size_t)j * 33;
#pragma unroll
    for (int i2 = 0; i2 < 32; i2++) acc += hl[r][i2] * w1r[i2];
    acc += as[r] * w1r[32];
    float o = tanhf(acc) * W2[j];
#pragma unroll
    for (int off = 16; off; off >>= 1) o += __shfl_xor(o, off, 32);
    if (j == 0) out[base + r] = o + b2[0];
}

// ---------------------------------------------------------------- launcher
extern "C" void kernel_launch(void* const* d_in, const int* in_sizes, int n_in,
                              void* d_out, int out_size, void* d_ws, size_t ws_size,
                              hipStream_t stream) {
    const float* x     = (const float*)d_in[0];
    const float* a     = (const float*)d_in[1];
    const float* m     = (const float*)d_in[2];
    const float* W_in  = (const float*)d_in[3];
    const float* b_in  = (const float*)d_in[4];
    const float* W_out = (const float*)d_in[5];
    const float* b_out = (const float*)d_in[6];
    const float* Wz    = (const float*)d_in[7];
    const float* bz    = (const float*)d_in[8];
    const float* Wr    = (const float*)d_in[9];
    const float* br    = (const float*)d_in[10];
    const float* Wt    = (const float*)d_in[11];
    const float* bt    = (const float*)d_in[12];
    const float* W1    = (const float*)d_in[13];
    const float* b1    = (const float*)d_in[14];
    const float* W2    = (const float*)d_in[15];
    const float* b2    = (const float*)d_in[16];
    float* out = (float*)d_out;

    char* ws = (char*)d_ws;
    float*    h         = (float*)(ws);                           // 4 MB
    float*    apart     = (float*)(ws + ((size_t)4  << 20));      // 64 MB (16 slabs)
    _Float16* sT_in_hi  = (_Float16*)(ws + ((size_t)68 << 20));   // 8 MB
    _Float16* sT_in_lo  = (_Float16*)(ws + ((size_t)76 << 20));   // 8 MB
    _Float16* sT_out_hi = (_Float16*)(ws + ((size_t)84 << 20));   // 8 MB
    _Float16* sT_out_lo = (_Float16*)(ws + ((size_t)92 << 20));   // 8 MB (100 MB)

    k_init_h<<<1024, 256, 0, stream>>>(x, h);
    for (int s = 0; s < NSTEPS; s++) {
        k_s<<<512, 256, 0, stream>>>(h, W_in, b_in, W_out, b_out,
                                     sT_in_hi, sT_in_lo, sT_out_hi, sT_out_lo);
        k_einsum_l<<<dim3(KSPLIT, 64, 2), 256, 0, stream>>>(m, sT_in_hi, sT_in_lo,
                                                            sT_out_hi, sT_out_lo,
                                                            apart);
        k_gate<<<4096, 256, 0, stream>>>(apart, h, Wz, bz, Wr, br, Wt, bt);
    }
    k_final<<<4096, 256, 0, stream>>>(h, a, W1, b1, W2, b2, out);
}